// Round 13
// baseline (155.259 us; speedup 1.0000x reference)
//
#include <hip/hip_runtime.h>
#include <hip/hip_fp16.h>

// CapsuleLayer dynamic routing — round 17 (corrected): keep r16's proven
// structure; accelerate RD0 with 2-b-per-wave (c=softmax(bias) is known
// upfront, so per-j butterfly with immediate scale works for 2 b off one W
// read -> RD0 waves halve, LDS reads halve). RD1/2 keep 1 b/wave (s is per-j
// and needs 1/Z known only after all j -> hat residency 40 regs caps at 1 b).
// Also: reduce kernels unchanged. Mid-write correctness catch: the "single
// accumulator over j" idea collapses the j dimension (s is per output
// capsule) — rejected; this version only exploits 2-b sharing where c is
// j-loop-invariant (RD0).

#define IC 1152
#define IE 8
#define NC 10
#define DV 16
#define NB 256
#define NW (IC * NC * IE * DV)  // 1,474,560
#define SOUT (NC * DV)          // 160
#define GPB (IC / 32)           // 36 row-groups
#define WSLOT (NC * 8 * 64)     // 5120 int4 = 80 KB per Gp slice
#define TPB0 512                // RD0: 8 waves x 2 b = 16 b/block
#define BPB0 16
#define TPB1 512                // RD1/2: 8 waves x 1 b = 8 b/block
#define BPB1 8

typedef _Float16 h2 __attribute__((ext_vector_type(2)));
union WChunk { int4 v; h2 p[4]; _Float16 h[8]; };
union XFrag { int4 v; h2 p[4]; };

#if defined(__has_builtin) && __has_builtin(__builtin_amdgcn_fdot2)
__device__ inline float fdot2(h2 a, h2 b, float c) {
    return __builtin_amdgcn_fdot2(a, b, c, false);
}
#else
__device__ inline float fdot2(h2 a, h2 b, float c) {
    return fmaf((float)a.x, (float)b.x, fmaf((float)a.y, (float)b.y, c));
}
#endif

// W fp32 [i][j][e][d] -> fp16 chunks Wc[((Gp*10+j)*8+k)*64 + lane], where
// lane = h*32+r, i = Gp*32+r, d = h*8+k; chunk holds e=0..7 halves of W[i,j,:,d].
__global__ void wprep_kernel(const float* __restrict__ W, int4* __restrict__ Wc) {
    const int t = blockIdx.x * blockDim.x + threadIdx.x;
    if (t >= NW / 8) return;
    const int lane = t & 63;
    const int h = lane >> 5, r = lane & 31;
    const int k = (t >> 6) & 7;
    const int r2 = t >> 9;  // Gp*10 + j
    const int j = r2 % NC, Gp = r2 / NC;
    const int i = Gp * 32 + r;
    const int d = h * 8 + k;
    const float* src = W + ((size_t)(i * NC + j) * IE) * DV + d;  // e-stride DV
    WChunk c;
#pragma unroll
    for (int e = 0; e < IE; ++e) c.h[e] = (_Float16)src[(size_t)e * DV];
    Wc[t] = c.v;
}

__device__ inline void butterfly_store(const float* s8, int r, float* dst8) {
    float t4[4];
#pragma unroll
    for (int d = 0; d < 4; ++d) {
        const bool hi = (r & 16);
        const float mine = hi ? s8[d + 4] : s8[d];
        const float send = hi ? s8[d] : s8[d + 4];
        t4[d] = mine + __shfl_xor(send, 16);
    }
    float t2[2];
#pragma unroll
    for (int d = 0; d < 2; ++d) {
        const bool hi = (r & 8);
        const float mine = hi ? t4[d + 2] : t4[d];
        const float send = hi ? t4[d] : t4[d + 2];
        t2[d] = mine + __shfl_xor(send, 8);
    }
    float t1;
    {
        const bool hi = (r & 4);
        const float mine = hi ? t2[1] : t2[0];
        const float send = hi ? t2[0] : t2[1];
        t1 = mine + __shfl_xor(send, 4);
    }
    t1 += __shfl_xor(t1, 2);
    t1 += __shfl_xor(t1, 1);
    if ((r & 3) == 0) {
        const int dl = (r >> 2) & 7;  // bit map: r4->d2, r3->d1, r2->d0
        dst8[dl] = t1;
    }
}

// RD0: c = softmax(bias) is j-loop-invariant -> 2 b per wave off one W read.
__global__ __launch_bounds__(TPB0) void round0_caps(
    const float* __restrict__ X, const int4* __restrict__ Wc,
    const float* __restrict__ bias, float* __restrict__ sp) {
    __shared__ __align__(16) int4 Ws[WSLOT];  // 80 KB

    const int Gp = blockIdx.x, bg = blockIdx.y;
    const int tid = threadIdx.x;
    const int w = tid >> 6, g = tid & 63;
    const int h = g >> 5, r = g & 31;

    {
        const int4* src = Wc + (size_t)Gp * WSLOT;
#pragma unroll
        for (int k = 0; k < WSLOT / TPB0; ++k)
            Ws[tid + k * TPB0] = src[tid + k * TPB0];
    }
    const int b0 = bg * BPB0 + 2 * w, b1 = b0 + 1;
    const int i = Gp * 32 + r;

    XFrag xu0, xu1;
    {
        const float4* xp = (const float4*)(X + ((size_t)b0 * IC + i) * IE);
        const float4 a0 = xp[0], a1 = xp[1];
        xu0.p[0] = h2{(_Float16)a0.x, (_Float16)a0.y};
        xu0.p[1] = h2{(_Float16)a0.z, (_Float16)a0.w};
        xu0.p[2] = h2{(_Float16)a1.x, (_Float16)a1.y};
        xu0.p[3] = h2{(_Float16)a1.z, (_Float16)a1.w};
        const float4* yp = (const float4*)(X + ((size_t)b1 * IC + i) * IE);
        const float4 c0 = yp[0], c1 = yp[1];
        xu1.p[0] = h2{(_Float16)c0.x, (_Float16)c0.y};
        xu1.p[1] = h2{(_Float16)c0.z, (_Float16)c0.w};
        xu1.p[2] = h2{(_Float16)c1.x, (_Float16)c1.y};
        xu1.p[3] = h2{(_Float16)c1.z, (_Float16)c1.w};
    }
    float cj[NC];
    {
        float Z = 0.f;
#pragma unroll
        for (int j = 0; j < NC; ++j) {
            const float e = __expf(bias[i * NC + j]);
            cj[j] = e;
            Z += e;
        }
        const float rz = 1.f / Z;
#pragma unroll
        for (int j = 0; j < NC; ++j) cj[j] *= rz;
    }
    __syncthreads();

    float* spb0 = sp + ((size_t)Gp * NB + b0) * SOUT + h * 8;
    float* spb1 = sp + ((size_t)Gp * NB + b1) * SOUT + h * 8;
#pragma unroll
    for (int j = 0; j < NC; ++j) {
        const int4* wp = Ws + j * 512 + g;
        float s80[8], s81[8];
#pragma unroll
        for (int kp = 0; kp < 4; ++kp) {
            WChunk wa, wb;
            wa.v = wp[(2 * kp) * 64];
            wb.v = wp[(2 * kp + 1) * 64];
            float a00 = 0.f, a01 = 0.f, a10 = 0.f, a11 = 0.f;
#pragma unroll
            for (int q = 0; q < 4; ++q) {
                a00 = fdot2(xu0.p[q], wa.p[q], a00);
                a01 = fdot2(xu0.p[q], wb.p[q], a01);
                a10 = fdot2(xu1.p[q], wa.p[q], a10);
                a11 = fdot2(xu1.p[q], wb.p[q], a11);
            }
            s80[2 * kp] = cj[j] * a00; s80[2 * kp + 1] = cj[j] * a01;
            s81[2 * kp] = cj[j] * a10; s81[2 * kp + 1] = cj[j] * a11;
        }
        butterfly_store(s80, r, spb0 + j * DV);
        butterfly_store(s81, r, spb1 + j * DV);
    }
}

// RD1/2: 1 b per wave (hat resident 40 h2; s per-j needs 1/Z after all j).
// Identical to r16's proven body.
__global__ __launch_bounds__(TPB1) void roundN_caps(
    const float* __restrict__ X, const int4* __restrict__ Wc,
    const float* __restrict__ bias, const float* __restrict__ vF,
    float* __restrict__ sp) {
    __shared__ __align__(16) int4 Ws[WSLOT];  // 80 KB

    const int Gp = blockIdx.x, bg = blockIdx.y;
    const int tid = threadIdx.x;
    const int w = tid >> 6, g = tid & 63;
    const int h = g >> 5, r = g & 31;

    {
        const int4* src = Wc + (size_t)Gp * WSLOT;
#pragma unroll
        for (int k = 0; k < WSLOT / TPB1; ++k)
            Ws[tid + k * TPB1] = src[tid + k * TPB1];
    }
    const int b = bg * BPB1 + w;
    const int i = Gp * 32 + r;

    XFrag xu;
    {
        const float4* xp = (const float4*)(X + ((size_t)b * IC + i) * IE);
        const float4 a0 = xp[0], a1 = xp[1];
        xu.p[0] = h2{(_Float16)a0.x, (_Float16)a0.y};
        xu.p[1] = h2{(_Float16)a0.z, (_Float16)a0.w};
        xu.p[2] = h2{(_Float16)a1.x, (_Float16)a1.y};
        xu.p[3] = h2{(_Float16)a1.z, (_Float16)a1.w};
    }
    __syncthreads();

    h2 hat2[NC][4];
    float cj[NC];
    float Z = 0.f;
#pragma unroll
    for (int j = 0; j < NC; ++j) {
        const int4* wp = Ws + j * 512 + g;
#pragma unroll
        for (int kp = 0; kp < 4; ++kp) {
            WChunk wa, wb;
            wa.v = wp[(2 * kp) * 64];
            wb.v = wp[(2 * kp + 1) * 64];
            float a0 = 0.f, a1 = 0.f;
#pragma unroll
            for (int q = 0; q < 4; ++q) {
                a0 = fdot2(xu.p[q], wa.p[q], a0);
                a1 = fdot2(xu.p[q], wb.p[q], a1);
            }
            hat2[j][kp] = h2{(_Float16)a0, (_Float16)a1};
        }
        const float4* vp = (const float4*)(vF + (size_t)b * SOUT + j * DV + h * 8);
        const float4 va = vp[0], vb = vp[1];
        float ah = (float)hat2[j][0].x * va.x + (float)hat2[j][0].y * va.y +
                   (float)hat2[j][1].x * va.z + (float)hat2[j][1].y * va.w +
                   (float)hat2[j][2].x * vb.x + (float)hat2[j][2].y * vb.y +
                   (float)hat2[j][3].x * vb.z + (float)hat2[j][3].y * vb.w;
        const float lt = bias[i * NC + j] + ah + __shfl_xor(ah, 32);
        const float e = __expf(lt);
        cj[j] = e;
        Z += e;
    }
    const float rz = 1.f / Z;

    float* spb = sp + ((size_t)Gp * NB + b) * SOUT + h * 8;
#pragma unroll
    for (int j = 0; j < NC; ++j) {
        const float cn = cj[j] * rz;
        float s8[8];
#pragma unroll
        for (int q = 0; q < 4; ++q) {
            s8[2 * q]     = cn * (float)hat2[j][q].x;
            s8[2 * q + 1] = cn * (float)hat2[j][q].y;
        }
        butterfly_store(s8, r, spb + j * DV);
    }
}

// Per-round reduce: v = squash(sum over 36 Gp partials) (+ vprev for P2).
template <int P>
__global__ __launch_bounds__(192) void reduce_caps(
    const float* __restrict__ sp, const float* __restrict__ vprevF,
    float* __restrict__ voutF, float* __restrict__ out) {
    const int b = blockIdx.x, t = threadIdx.x;
    if (t >= SOUT) return;
    float sv = 0.f;
#pragma unroll
    for (int gq = 0; gq < GPB; ++gq) sv += sp[((size_t)gq * NB + b) * SOUT + t];
    float s2 = sv * sv;
#pragma unroll
    for (int mk = 8; mk >= 1; mk >>= 1) s2 += __shfl_xor(s2, mk, 16);
    float vv = sqrtf(s2) / (1.f + s2) * sv;
    if constexpr (P == 2) vv += vprevF[(size_t)b * SOUT + t];  // vsum = v1+v2
    if constexpr (P == 3) out[(size_t)b * SOUT + t] = vv;
    else voutF[(size_t)b * SOUT + t] = vv;
}

extern "C" void kernel_launch(void* const* d_in, const int* in_sizes, int n_in,
                              void* d_out, int out_size, void* d_ws, size_t ws_size,
                              hipStream_t stream) {
    const float* X = (const float*)d_in[0];     // [256,1152,8]
    const float* W = (const float*)d_in[1];     // [1152,10,8,16]
    const float* bias = (const float*)d_in[2];  // [1,1152,10]
    float* out = (float*)d_out;

    // ws: Wc 2.95MB | sp 5.9MB (reused each round) | v1F 160KB | vsF 160KB
    int4* Wc = (int4*)d_ws;
    float* sp = (float*)(Wc + NW / 8);
    float* v1F = sp + (size_t)GPB * NB * SOUT;
    float* vsF = v1F + (size_t)NB * SOUT;

    wprep_kernel<<<dim3(720), dim3(256), 0, stream>>>(W, Wc);

    round0_caps<<<dim3(GPB, NB / BPB0), TPB0, 0, stream>>>(X, Wc, bias, sp);
    reduce_caps<1><<<dim3(NB), dim3(192), 0, stream>>>(sp, nullptr, v1F, nullptr);
    roundN_caps<<<dim3(GPB, NB / BPB1), TPB1, 0, stream>>>(X, Wc, bias, v1F, sp);
    reduce_caps<2><<<dim3(NB), dim3(192), 0, stream>>>(sp, v1F, vsF, nullptr);
    roundN_caps<<<dim3(GPB, NB / BPB1), TPB1, 0, stream>>>(X, Wc, bias, vsF, sp);
    reduce_caps<3><<<dim3(NB), dim3(192), 0, stream>>>(sp, nullptr, nullptr, out);
}